// Round 10
// baseline (256.399 us; speedup 1.0000x reference)
//
#include <hip/hip_runtime.h>
#include <stdint.h>

#define M_DIM 4096
#define T_DIM 2048
#define N_OUT 2024
#define N_PAD 2048
#define WIN   25
#define K_DIM 4096

typedef float f32x4 __attribute__((ext_vector_type(4)));
typedef int   i32x8 __attribute__((ext_vector_type(8)));

__device__ __forceinline__ unsigned short f2bf(float x) {
  unsigned u = __float_as_uint(x);
  u += 0x7FFF + ((u >> 16) & 1);           // round-to-nearest-even
  return (unsigned short)(u >> 16);
}
__device__ __forceinline__ float bf2f(unsigned short h) {
  return __uint_as_float(((unsigned)h) << 16);
}

__device__ __forceinline__ void gl2lds16(const void* g, void* l) {
  // 16B-wide async global->LDS; HW dest = wave-uniform base + lane*16
  __builtin_amdgcn_global_load_lds(
      (const __attribute__((address_space(1))) unsigned int*)g,
      (__attribute__((address_space(3))) unsigned int*)l, 16, 0, 0);
}

// pack 4 floats -> 4 e4m3 bytes (one dword)
__device__ __forceinline__ int pk_fp8x4(float a, float b, float c, float d) {
  int w = __builtin_amdgcn_cvt_pk_fp8_f32(a, b, 0, false);
  w = __builtin_amdgcn_cvt_pk_fp8_f32(c, d, w, true);
  return w;
}

// ---------- Kernel 1: W8 = e4m3(sigmoid(alphas)), diagonal -> 0 ----------
__global__ __launch_bounds__(256) void k_wcast(const float* __restrict__ alphas,
                                               unsigned char* __restrict__ W8) {
  size_t i8 = ((size_t)blockIdx.x * 256 + threadIdx.x) * 8;
  const float4 v0 = *(const float4*)(alphas + i8);
  const float4 v1 = *(const float4*)(alphas + i8 + 4);
  int row = (int)(i8 >> 12);
  int col = (int)(i8 & 4095);
  float a[8] = {v0.x, v0.y, v0.z, v0.w, v1.x, v1.y, v1.z, v1.w};
  float w[8];
#pragma unroll
  for (int j = 0; j < 8; ++j)
    w[j] = (row == col + j) ? 0.f : 1.f / (1.f + __expf(-a[j]));
  int p0 = pk_fp8x4(w[0], w[1], w[2], w[3]);
  int p1 = pk_fp8x4(w[4], w[5], w[6], w[7]);
  *(uint2*)(W8 + i8) = uint2{(unsigned)p0, (unsigned)p1};
}

// ---------- Kernel 2: merged conv + transpose (ys read ONCE) ----------
// R13 version verbatim (passed three times).
__global__ __launch_bounds__(256) void k_convT(const float* __restrict__ ys,
                                               const float* __restrict__ repro,
                                               unsigned short* __restrict__ Sbf,
                                               unsigned char* __restrict__ BT8) {
  __shared__ float sy[32][284];   // 280 used + pad
  __shared__ float sr[32][26];
  const int tid = threadIdx.x;
  const int c0 = blockIdx.x * 256;   // 0..7 -> col chunk
  const int m0 = blockIdx.y * 32;    // 0..127 -> row chunk

  for (int slot = tid; slot < 32 * 70; slot += 256) {
    int r = slot / 70, f = slot % 70;
    int c = c0 + f * 4;
    float4 v = (c < T_DIM) ? *(const float4*)(ys + (size_t)(m0 + r) * T_DIM + c)
                           : float4{0.f, 0.f, 0.f, 0.f};
    sy[r][f * 4 + 0] = v.x; sy[r][f * 4 + 1] = v.y;
    sy[r][f * 4 + 2] = v.z; sy[r][f * 4 + 3] = v.w;
  }
  for (int slot = tid; slot < 32 * WIN; slot += 256) {
    int r = slot / WIN, k = slot % WIN;
    sr[r][k] = repro[(m0 + r) * WIN + k];
  }
  __syncthreads();

  // ---- conv ----
  {
    const int r = tid >> 3;
    const int cbase = (tid & 7) * 32;
    float y[56];
#pragma unroll
    for (int i = 0; i < 56; ++i) y[i] = sy[r][cbase + i];
    float rv[WIN];
#pragma unroll
    for (int k = 0; k < WIN; ++k) rv[k] = sr[r][k];
    unsigned pk[16];
#pragma unroll
    for (int jj = 0; jj < 32; ++jj) {
      float z = 0.f;
#pragma unroll
      for (int k = 0; k < WIN; ++k) z += y[jj + k] * rv[k];   // same k-order as R0
      float sp = fmaxf(z, 0.f) + log1pf(__expf(-fabsf(z)));
      int gj = c0 + cbase + jj;
      unsigned short h = (gj < N_OUT) ? f2bf(sp) : (unsigned short)0;
      if (jj & 1) pk[jj >> 1] |= ((unsigned)h) << 16;
      else        pk[jj >> 1]  = (unsigned)h;
    }
    unsigned short* dst = Sbf + (size_t)(m0 + r) * N_PAD + c0 + cbase;
    *(uint4*)(dst)      = *(const uint4*)(pk + 0);
    *(uint4*)(dst + 8)  = *(const uint4*)(pk + 4);
    *(uint4*)(dst + 16) = *(const uint4*)(pk + 8);
    *(uint4*)(dst + 24) = *(const uint4*)(pk + 12);
  }

  // ---- BT8 ----
  {
    const int n = c0 + tid;
    const bool ok = (n < N_OUT);
    unsigned w[8];
#pragma unroll
    for (int i = 0; i < 8; ++i) {
      float a0 = ok ? sy[4 * i + 0][tid + 24] : 0.f;
      float a1 = ok ? sy[4 * i + 1][tid + 24] : 0.f;
      float a2 = ok ? sy[4 * i + 2][tid + 24] : 0.f;
      float a3 = ok ? sy[4 * i + 3][tid + 24] : 0.f;
      w[i] = (unsigned)pk_fp8x4(a0, a1, a2, a3);
    }
    unsigned char* dst = BT8 + (size_t)n * K_DIM + m0;
    *(uint4*)(dst)      = uint4{w[0], w[1], w[2], w[3]};
    *(uint4*)(dst + 16) = uint4{w[4], w[5], w[6], w[7]};
  }
}

// ---------- GEMM: C = W8 @ BT8^T (MX fp8 MFMA), out = beta * (S + C) ----------
// R17: MX-scaled K=128 MFMA on the R16 structure. Evidence: R16 sits at
// 834 TF = the known ~900 TF ceiling of the 2-barrier structure (m99-m141:
// all schedule variants 839-890); geometry sweep (R9/R11/R15) done. The
// proven on-structure escape is the MFMA rate: m145->m148 ported THIS
// structure fp8->MX-fp8 K=128 for 995->1628 TF. R16 already stages BK=128
// and reads 4 x b64 sub-fragments per kstep -> pack into v8i32, issue ONE
// mfma_scale_f32_16x16x128_f8f6f4 (cbsz=0/blgp=0 = e4m3 both; scales
// 0x7F = 1.0). Correctness is layout-permutation-safe: A and B carry
// k-values in identical register positions and dot products are invariant
// under a common k-permutation; identity scales make the HW block-scale
// mapping irrelevant. Only intra-instruction f32 reduction order changes
// (<< fp8 quantization already tolerated). Everything else R16-verbatim.
__global__ __launch_bounds__(512, 4) void k_gemm(const unsigned char* __restrict__ W8,
                                                 const unsigned char* __restrict__ BT8,
                                                 const unsigned short* __restrict__ Sbf,
                                                 const float* __restrict__ b0,
                                                 const float* __restrict__ b1,
                                                 float* __restrict__ out) {
  __shared__ __align__(64) unsigned char lA[2][128 * 128];   // 32 KB
  __shared__ __align__(64) unsigned char lB[2][128 * 128];   // 32 KB
  const int tid  = threadIdx.x;
  const int wave = tid >> 6;          // 0..7
  const int lane = tid & 63;
  const int wm = wave >> 2;           // 0..1 : 64-row slice
  const int wn = wave & 3;            // 0..3 : 32-col slice
  const int m16  = lane & 15;
  const int quad = lane >> 4;

  // XCD-aware bijective swizzle (512%8==0): each XCD gets 64 consecutive
  // tiles = 4 full M-rows -> A-panels L2-local.
  const int fid  = blockIdx.y * gridDim.x + blockIdx.x;   // 0..511
  const int swz  = (fid & 7) * 64 + (fid >> 3);
  const int tileN = (swz & 15) * 128;
  const int tileM = (swz >> 4) * 128;

  // fragment read offsets: 128B rows (K=128 fp8 per kstep).
  // k-chunk h (K=32 each, h=0..3): lane reads bytes k = h*32 + quad*8 .. +7
  // chunk c = 2h + (quad>>1) in 0..7; swizzled slot = c ^ ((row>>1)&7);
  // (row>>1)&7 == (m16>>1)&7 for every fragment row.
  const int key  = (m16 >> 1) & 7;
  const int sub  = (quad & 1) * 8;
  const int rowA = (wm * 64 + m16) * 128;
  const int rowB = (wn * 32 + m16) * 128;
  int hOf[4];
#pragma unroll
  for (int h = 0; h < 4; ++h)
    hOf[h] = (((2 * h + (quad >> 1)) ^ key) << 4) + sub;

  // staging: 2 chunks/thread/matrix (16 KB per matrix per kstep).
  // Global addr carries the XOR swizzle; LDS dest stays linear.
  const unsigned char* gA[2];
  const unsigned char* gB[2];
  int ldsBase[2];                          // wave-uniform (HW adds lane*16)
#pragma unroll
  for (int c = 0; c < 2; ++c) {
    int o = c * 8192 + wave * 1024 + lane * 16;   // 0..16383
    int r = o >> 7;                     // row 0..127 (128B rows)
    int s = (o >> 4) & 7;               // LDS chunk slot 0..7
    int q = s ^ ((r >> 1) & 7);         // logical (global) chunk
    gA[c] = W8  + (size_t)(tileM + r) * K_DIM + q * 16;
    gB[c] = BT8 + (size_t)(tileN + r) * K_DIM + q * 16;
    ldsBase[c] = c * 8192 + wave * 1024;
  }

  f32x4 acc[4][2];
#pragma unroll
  for (int i = 0; i < 4; ++i)
#pragma unroll
    for (int j = 0; j < 2; ++j) acc[i][j] = f32x4{0.f, 0.f, 0.f, 0.f};

  // 4 gl2lds (vmcnt events) per tile per thread
  auto stage = [&](int buf, int kt_) {
    const size_t kb_ = (size_t)kt_ * 128;
#pragma unroll
    for (int c = 0; c < 2; ++c) {
      gl2lds16(gA[c] + kb_, &lA[buf][ldsBase[c]]);
      gl2lds16(gB[c] + kb_, &lB[buf][ldsBase[c]]);
    }
  };
  auto compute = [&](int buf) {
    i32x8 aP[4], bP[2];
#pragma unroll
    for (int i = 0; i < 4; ++i) {
#pragma unroll
      for (int h = 0; h < 4; ++h) {
        long long v = *(const long long*)&lA[buf][rowA + i * 2048 + hOf[h]];
        aP[i][2 * h]     = (int)(unsigned)(v & 0xFFFFFFFFull);
        aP[i][2 * h + 1] = (int)(unsigned)((unsigned long long)v >> 32);
      }
    }
#pragma unroll
    for (int j = 0; j < 2; ++j) {
#pragma unroll
      for (int h = 0; h < 4; ++h) {
        long long v = *(const long long*)&lB[buf][rowB + j * 2048 + hOf[h]];
        bP[j][2 * h]     = (int)(unsigned)(v & 0xFFFFFFFFull);
        bP[j][2 * h + 1] = (int)(unsigned)((unsigned long long)v >> 32);
      }
    }
#pragma unroll
    for (int i = 0; i < 4; ++i)
#pragma unroll
      for (int j = 0; j < 2; ++j)
        acc[i][j] = __builtin_amdgcn_mfma_scale_f32_16x16x128_f8f6f4(
            aP[i], bP[j], acc[i][j], 0 /*cbsz: e4m3*/, 0 /*blgp: e4m3*/,
            0, 0x7F7F7F7F /*scaleA = 1.0*/, 0, 0x7F7F7F7F /*scaleB = 1.0*/);
  };

  // prologue: tile 0 in flight (4 outstanding per thread)
  stage(0, 0);

#pragma unroll 1
  for (int kt = 0; kt < K_DIM / 128; kt += 2) {
    // even phase: prefetch kt+1 -> buf1 (kt<=30 -> valid), compute buf0
    stage(1, kt + 1);                                  // 8 outstanding
    asm volatile("s_waitcnt vmcnt(4)" ::: "memory");   // tile kt landed
    __builtin_amdgcn_s_barrier();
    asm volatile("" ::: "memory");
    compute(0);
    __builtin_amdgcn_s_barrier();                      // buf0 free for reuse
    asm volatile("" ::: "memory");

    // odd phase: prefetch kt+2 -> buf0, compute buf1
    if (kt + 2 < K_DIM / 128) {
      stage(0, kt + 2);
      asm volatile("s_waitcnt vmcnt(4)" ::: "memory");
    } else {
      asm volatile("s_waitcnt vmcnt(0)" ::: "memory");
    }
    __builtin_amdgcn_s_barrier();
    asm volatile("" ::: "memory");
    compute(1);
    __builtin_amdgcn_s_barrier();
    asm volatile("" ::: "memory");
  }

  // Epilogue: out[gm][gn] = softplus(b0+b1*(gn+25)) * (S[gm][gn] + C)
#pragma unroll
  for (int j = 0; j < 2; ++j) {
    int gn = tileN + wn * 32 + j * 16 + m16;
    if (gn >= N_OUT) continue;
    float tval = (float)(gn + WIN);
#pragma unroll
    for (int i = 0; i < 4; ++i) {
#pragma unroll
      for (int r2 = 0; r2 < 4; ++r2) {
        int gm = tileM + wm * 64 + i * 16 + quad * 4 + r2;
        float x = b0[gm] + b1[gm] * tval;
        float beta = fmaxf(x, 0.f) + log1pf(__expf(-fabsf(x)));
        float sv = bf2f(Sbf[(size_t)gm * N_PAD + gn]);
        out[(size_t)gm * N_OUT + gn] = beta * (sv + acc[i][j][r2]);
      }
    }
  }
}

extern "C" void kernel_launch(void* const* d_in, const int* in_sizes, int n_in,
                              void* d_out, int out_size, void* d_ws, size_t ws_size,
                              hipStream_t stream) {
  const float* ys     = (const float*)d_in[0];
  const float* alphas = (const float*)d_in[1];
  const float* repro  = (const float*)d_in[2];
  const float* b0     = (const float*)d_in[3];
  const float* b1     = (const float*)d_in[4];
  float* out = (float*)d_out;

  char* ws = (char*)d_ws;
  unsigned char*  W8  = (unsigned char*)ws;                                    // 16 MiB
  unsigned char*  BT8 = (unsigned char*)(ws + (size_t)M_DIM * K_DIM);          //  8 MiB
  unsigned short* Sbf = (unsigned short*)(ws + (size_t)M_DIM * K_DIM
                                             + (size_t)N_PAD * K_DIM);         // 16 MiB

  k_wcast<<<(M_DIM * (size_t)K_DIM) / 8 / 256, 256, 0, stream>>>(alphas, W8);
  k_convT<<<dim3(T_DIM / 256, M_DIM / 32), 256, 0, stream>>>(ys, repro, Sbf, BT8);
  k_gemm<<<dim3(N_PAD / 128, M_DIM / 128), 512, 0, stream>>>(W8, BT8, Sbf,
                                                             b0, b1, out);
}